// Round 20
// baseline (99.959 us; speedup 1.0000x reference)
//
#include <hip/hip_runtime.h>
#include <hip/hip_bf16.h>

// Problem constants
#define HID 512
#define SEQ 2048
#define NG 32            // (B*NUM_HEADS) after the faithful-to-source flat reshape
#define HD 64
#define MROWS 8192       // B*SEQ
#define LDP 72           // padded LDS row stride (elems) = 144B
// 1/sqrt(512) * log2(e): folded into Q so softmax is exp2(s)
#define QSC 0.0637587178f
#define IDXN 2304        // padded idx length (2048 + slack)

typedef __bf16 bf16x8 __attribute__((ext_vector_type(8)));
typedef float f32x4 __attribute__((ext_vector_type(4)));

#define MFMA(a, b, c) __builtin_amdgcn_mfma_f32_16x16x32_bf16((a), (b), (c), 0, 0, 0)

// ---------------------------------------------------------------------------
// mask_scan: one block. hdr[0]=nvalid; idx=hdr+1 (gather list, 0-padded);
// cidx=hdr+1+IDXN (scatter map: key i -> compact pos, -1 if masked).
// ---------------------------------------------------------------------------
__global__ __launch_bounds__(256) void mask_scan(const int* __restrict__ mask,
                                                 int* __restrict__ hdr) {
    __shared__ int s[256];
    const int tid = threadIdx.x;
    const int base = tid * 8;
    int loc[8], cnt = 0;
    for (int j = 0; j < 8; ++j) { loc[j] = cnt; cnt += (mask[base + j] != 0); }
    s[tid] = cnt;
    __syncthreads();
    for (int off = 1; off < 256; off <<= 1) {
        int v = (tid >= off) ? s[tid - off] : 0;
        __syncthreads();
        s[tid] += v;
        __syncthreads();
    }
    const int excl = s[tid] - cnt;
    const int nvalid = s[255];
    int* idx = hdr + 1;
    int* cidx = hdr + 1 + IDXN;
    for (int j = 0; j < 8; ++j) {
        int i = base + j;
        bool v = (mask[i] != 0);
        cidx[i] = v ? (excl + loc[j]) : -1;
        if (v) idx[excl + loc[j]] = i;
    }
    if (tid == 0) hdr[0] = nvalid;
    __syncthreads();
    for (int p = nvalid + tid; p < IDXN; p += 256) idx[p] = 0;
}

// ---------------------------------------------------------------------------
// kv_pad: zero vT's pad COLUMNS [nvalid, ceil64) and kcomp's pad ROWS
// [nvalid, ceil64). Both buffers hold stale bytes between replays (vT in
// d_out; kcomp's masked rows never written) — stale bf16 NaN would poison
// QK^T/PV accumulators (round-17 lesson: every byte read must be written
// by the same call).
// ---------------------------------------------------------------------------
__global__ __launch_bounds__(256) void kv_pad(__hip_bfloat16* __restrict__ vT,
                                              __hip_bfloat16* __restrict__ kc,
                                              const int* __restrict__ hdr) {
    const int nvalid = hdr[0];
    const int cend = (nvalid + 63) & ~63;
    if (cend == nvalid) return;
    const int g = blockIdx.x;
    const __hip_bfloat16 z = (__hip_bfloat16)0.0f;
    for (int d = 0; d < HD; ++d)
        for (int c = nvalid + threadIdx.x; c < cend; c += 256)
            vT[(size_t)g * (HD * SEQ) + (size_t)d * SEQ + c] = z;
    // kcomp pad rows are contiguous: (cend-nvalid)*64 elems starting at row nvalid
    const int ne = (cend - nvalid) * HD;
    __hip_bfloat16* kp = kc + ((size_t)g * SEQ + nvalid) * HD;
    for (int e = threadIdx.x; e < ne; e += 256) kp[e] = z;
}

// ---------------------------------------------------------------------------
// prep: merged f32->bf16 converts. Blocks [0,2048): X (grid-stride);
// blocks [2048,3072): the four 512x512 weights into contiguous Wcat.
// ---------------------------------------------------------------------------
__global__ __launch_bounds__(256) void prep(const float* __restrict__ X,
                                            const float* __restrict__ Wq,
                                            const float* __restrict__ Wk,
                                            const float* __restrict__ Wv,
                                            const float* __restrict__ Wo,
                                            __hip_bfloat16* __restrict__ Xb,
                                            __hip_bfloat16* __restrict__ Wc) {
    const int b = blockIdx.x;
    if (b < 2048) {
        const int n4 = (MROWS * HID) / 4;
        for (int i = b * 256 + threadIdx.x; i < n4; i += 2048 * 256) {
            float4 v = *(const float4*)(X + (size_t)i * 4);
            union { __hip_bfloat16 h[4]; uint2 u; } p;
            p.h[0] = __float2bfloat16(v.x); p.h[1] = __float2bfloat16(v.y);
            p.h[2] = __float2bfloat16(v.z); p.h[3] = __float2bfloat16(v.w);
            *(uint2*)(Xb + (size_t)i * 4) = p.u;
        }
    } else {
        const int wb = b - 2048;
        const int which = wb >> 8;
        const float* s = which == 0 ? Wq : (which == 1 ? Wk : (which == 2 ? Wv : Wo));
        __hip_bfloat16* o = Wc + (size_t)which * (HID * HID);
        const int i = (wb & 255) * 256 + threadIdx.x;
        float4 v = *(const float4*)(s + (size_t)i * 4);
        union { __hip_bfloat16 h[4]; uint2 u; } p;
        p.h[0] = __float2bfloat16(v.x); p.h[1] = __float2bfloat16(v.y);
        p.h[2] = __float2bfloat16(v.z); p.h[3] = __float2bfloat16(v.w);
        *(uint2*)(o + (size_t)i * 4) = p.u;
    }
}

// ---------------------------------------------------------------------------
// Fused QKV GEMM, swapped MFMA operands (vector q/k stores). BOTH k and v are
// written compacted: k rows and vT columns only for valid keys (ci >= 0), at
// their compact position. attn then reads K and V contiguously — no gather.
// ---------------------------------------------------------------------------
__global__ __launch_bounds__(256) void gemm_qkv_fused(
        const __hip_bfloat16* __restrict__ Xb,
        const __hip_bfloat16* __restrict__ Wqb, const __hip_bfloat16* __restrict__ Wkb,
        const __hip_bfloat16* __restrict__ Wvb,
        const float* __restrict__ bq, const float* __restrict__ bk, const float* __restrict__ bv,
        const int* __restrict__ hdr,
        __hip_bfloat16* __restrict__ qout, __hip_bfloat16* __restrict__ kc,
        __hip_bfloat16* __restrict__ vT) {
    __shared__ __hip_bfloat16 Xs[64][LDP];
    __shared__ __hip_bfloat16 Wqs[64][LDP];
    __shared__ __hip_bfloat16 Wks[64][LDP];
    __shared__ __hip_bfloat16 Wvs[64][LDP];
    const int tid = threadIdx.x;
    const int w = tid >> 6, l = tid & 63;
    const int h = l >> 4, q = l & 15;
    const int row0 = blockIdx.x * 64, col0 = blockIdx.y * 64;

    const int r0 = tid >> 3, r1 = (tid + 256) >> 3;
    const int cc0 = (tid & 7) * 8;
    uint4 px0, px1, pq0, pq1, pk0, pk1, pv0, pv1;
    {
        px0 = *(const uint4*)(Xb  + (size_t)(row0 + r0) * HID + cc0);
        px1 = *(const uint4*)(Xb  + (size_t)(row0 + r1) * HID + cc0);
        pq0 = *(const uint4*)(Wqb + (size_t)(col0 + r0) * HID + cc0);
        pq1 = *(const uint4*)(Wqb + (size_t)(col0 + r1) * HID + cc0);
        pk0 = *(const uint4*)(Wkb + (size_t)(col0 + r0) * HID + cc0);
        pk1 = *(const uint4*)(Wkb + (size_t)(col0 + r1) * HID + cc0);
        pv0 = *(const uint4*)(Wvb + (size_t)(col0 + r0) * HID + cc0);
        pv1 = *(const uint4*)(Wvb + (size_t)(col0 + r1) * HID + cc0);
    }

    f32x4 aq[4] = {}, ak[4] = {}, av[4] = {};
    for (int kt = 0; kt < 8; ++kt) {
        __syncthreads();
        *(uint4*)&Xs[r0][cc0]  = px0;  *(uint4*)&Xs[r1][cc0]  = px1;
        *(uint4*)&Wqs[r0][cc0] = pq0;  *(uint4*)&Wqs[r1][cc0] = pq1;
        *(uint4*)&Wks[r0][cc0] = pk0;  *(uint4*)&Wks[r1][cc0] = pk1;
        *(uint4*)&Wvs[r0][cc0] = pv0;  *(uint4*)&Wvs[r1][cc0] = pv1;
        __syncthreads();
        if (kt < 7) {
            size_t go = (size_t)(kt + 1) * 64 + cc0;
            px0 = *(const uint4*)(Xb  + (size_t)(row0 + r0) * HID + go);
            px1 = *(const uint4*)(Xb  + (size_t)(row0 + r1) * HID + go);
            pq0 = *(const uint4*)(Wqb + (size_t)(col0 + r0) * HID + go);
            pq1 = *(const uint4*)(Wqb + (size_t)(col0 + r1) * HID + go);
            pk0 = *(const uint4*)(Wkb + (size_t)(col0 + r0) * HID + go);
            pk1 = *(const uint4*)(Wkb + (size_t)(col0 + r1) * HID + go);
            pv0 = *(const uint4*)(Wvb + (size_t)(col0 + r0) * HID + go);
            pv1 = *(const uint4*)(Wvb + (size_t)(col0 + r1) * HID + go);
        }
        for (int dk = 0; dk < 2; ++dk) {
            bf16x8 x = *(const bf16x8*)&Xs[w * 16 + q][dk * 32 + 8 * h];
            for (int nt = 0; nt < 4; ++nt) {
                int rr = nt * 16 + q, cc = dk * 32 + 8 * h;
                aq[nt] = MFMA(*(const bf16x8*)&Wqs[rr][cc], x, aq[nt]);
                ak[nt] = MFMA(*(const bf16x8*)&Wks[rr][cc], x, ak[nt]);
                av[nt] = MFMA(*(const bf16x8*)&Wvs[rr][cc], x, av[nt]);
            }
        }
    }
    // epilogue: lane row m = row0 + w*16 + q; cols n = col0 + nt*16 + 4h + jj
    const int m = row0 + w * 16 + q;
    const int g = row0 >> 8;
    const int irow = ((m & 255) << 3) + (int)blockIdx.y;   // key index i
    const int ci = hdr[1 + IDXN + irow];                   // compact pos (-1 = masked)
    for (int nt = 0; nt < 4; ++nt) {
        int nb = col0 + nt * 16 + 4 * h;
        float4 b4q = *(const float4*)(bq + nb);
        float4 b4k = *(const float4*)(bk + nb);
        float4 b4v = *(const float4*)(bv + nb);
        const float* bqf = (const float*)&b4q;
        const float* bkf = (const float*)&b4k;
        const float* bvf = (const float*)&b4v;
        union { __hip_bfloat16 hh[4]; uint2 u; } oq, ok;
        for (int jj = 0; jj < 4; ++jj) {
            oq.hh[jj] = __float2bfloat16((aq[nt][jj] + bqf[jj]) * QSC);
            ok.hh[jj] = __float2bfloat16(ak[nt][jj] + bkf[jj]);
        }
        *(uint2*)(qout + (size_t)m * HID + nb) = oq.u;
        if (ci >= 0) {
            int db = nb & 63;   // col0 is a multiple of 64
            *(uint2*)(kc + ((size_t)g * SEQ + ci) * HD + db) = ok.u;
            for (int jj = 0; jj < 4; ++jj)
                vT[(size_t)g * (HD * SEQ) + (size_t)(db + jj) * SEQ + ci] =
                    __float2bfloat16(av[nt][jj] + bvf[jj]);
        }
    }
}

// ---------------------------------------------------------------------------
// GEMM: out_f32[M x 512] = X_bf16 @ Wo_bf16^T + bo. Swapped operands ->
// float4 (16B) contiguous output stores.
// ---------------------------------------------------------------------------
__global__ __launch_bounds__(256) void gemm_out(const __hip_bfloat16* __restrict__ X,
                                                const __hip_bfloat16* __restrict__ W,
                                                const float* __restrict__ bias,
                                                float* __restrict__ out) {
    __shared__ __hip_bfloat16 Xs[64][LDP];
    __shared__ __hip_bfloat16 Ws[64][LDP];
    const int tid = threadIdx.x;
    const int w = tid >> 6, l = tid & 63;
    const int h = l >> 4, q = l & 15;
    const int row0 = blockIdx.x * 64, col0 = blockIdx.y * 64;

    const int r0 = tid >> 3, r1 = (tid + 256) >> 3;
    const int cc0 = (tid & 7) * 8;
    uint4 px0 = *(const uint4*)(X + (size_t)(row0 + r0) * HID + cc0);
    uint4 px1 = *(const uint4*)(X + (size_t)(row0 + r1) * HID + cc0);
    uint4 pw0 = *(const uint4*)(W + (size_t)(col0 + r0) * HID + cc0);
    uint4 pw1 = *(const uint4*)(W + (size_t)(col0 + r1) * HID + cc0);

    f32x4 acc[4] = {};
    for (int kt = 0; kt < 8; ++kt) {
        __syncthreads();
        *(uint4*)&Xs[r0][cc0] = px0;  *(uint4*)&Xs[r1][cc0] = px1;
        *(uint4*)&Ws[r0][cc0] = pw0;  *(uint4*)&Ws[r1][cc0] = pw1;
        __syncthreads();
        if (kt < 7) {
            size_t go = (size_t)(kt + 1) * 64 + cc0;
            px0 = *(const uint4*)(X + (size_t)(row0 + r0) * HID + go);
            px1 = *(const uint4*)(X + (size_t)(row0 + r1) * HID + go);
            pw0 = *(const uint4*)(W + (size_t)(col0 + r0) * HID + go);
            pw1 = *(const uint4*)(W + (size_t)(col0 + r1) * HID + go);
        }
        for (int dk = 0; dk < 2; ++dk) {
            bf16x8 x = *(const bf16x8*)&Xs[w * 16 + q][dk * 32 + 8 * h];
            for (int nt = 0; nt < 4; ++nt) {
                bf16x8 b = *(const bf16x8*)&Ws[nt * 16 + q][dk * 32 + 8 * h];
                acc[nt] = MFMA(b, x, acc[nt]);
            }
        }
    }
    const int m = row0 + w * 16 + q;
    for (int nt = 0; nt < 4; ++nt) {
        int nb = col0 + nt * 16 + 4 * h;
        float4 b4 = *(const float4*)(bias + nb);
        float4 o = make_float4(acc[nt][0] + b4.x, acc[nt][1] + b4.y,
                               acc[nt][2] + b4.z, acc[nt][3] + b4.w);
        *(float4*)(out + (size_t)m * HID + nb) = o;
    }
}

// ---------------------------------------------------------------------------
// Attention over COMPACTED keys, ntiles = ceil(nvalid/64). K AND V both
// pre-compacted at the GEMM epilogue -> all staging loads are contiguous,
// no gather, no idx[] in the hot loop. Tail pad keys masked via sbias and
// zeroed pad rows/cols (kv_pad). Swapped-QK^T in-register softmax.
// ---------------------------------------------------------------------------
__global__ __launch_bounds__(256) void attn(const __hip_bfloat16* __restrict__ qg,
                                            const __hip_bfloat16* __restrict__ kc,
                                            const __hip_bfloat16* __restrict__ vT,
                                            const int* __restrict__ hdr,
                                            __hip_bfloat16* __restrict__ wvt) {
    __shared__ __hip_bfloat16 Ks[2][64][LDP];
    __shared__ __hip_bfloat16 VTs[2][64][LDP];
    __shared__ float sb[2][64];

    const int tid = threadIdx.x;
    const int w = tid >> 6, l = tid & 63;
    const int h = l >> 4, q = l & 15;
    // XCD-chunked swizzle: 512 blocks % 8 == 0 -> bijective
    const int bid = (blockIdx.x & 7) * 64 + (blockIdx.x >> 3);
    const int g = bid >> 4, qt = bid & 15;
    const size_t hb = (size_t)g * (SEQ * HD);

    const int nvalid = hdr[0];
    const int ntiles = (nvalid + 63) >> 6;

    // Q fragments in registers (one-time global read, L2-resident)
    bf16x8 qf[2][2];
    for (int m = 0; m < 2; ++m)
        for (int dk = 0; dk < 2; ++dk)
            qf[m][dk] = *(const bf16x8*)(qg + hb +
                (size_t)(qt * 128 + w * 32 + m * 16 + q) * HD + dk * 32 + 8 * h);

    const int r0 = tid >> 3, r1 = (tid + 256) >> 3;
    const int cc0 = (tid & 7) * 8;
    // permuted V dest base: keys cc0..cc0+3 -> cA..cA+3, cc0+4..+7 -> cA+8..+11
    const int ntc = cc0 >> 4;
    const int cA = (ntc & 1) * 32 + ((cc0 >> 2) & 3) * 8 + (ntc >> 1) * 4;

    const __bf16 kOne = (__bf16)1.0f;
    const bf16x8 ones = {kOne, kOne, kOne, kOne, kOne, kOne, kOne, kOne};

    f32x4 acc[2][4] = {};
    f32x4 lsum[2] = {};

    // ---- prologue: tile 0 into buf 0; tile 1 into regs ----
    uint4 kp0 = *(const uint4*)(kc + hb + (size_t)r0 * HD + cc0);
    uint4 kp1 = *(const uint4*)(kc + hb + (size_t)r1 * HD + cc0);
    uint4 vp0 = *(const uint4*)(vT + hb + (size_t)r0 * SEQ + cc0);
    uint4 vp1 = *(const uint4*)(vT + hb + (size_t)r1 * SEQ + cc0);

    *(uint4*)&Ks[0][r0][cc0] = kp0;
    *(uint4*)&Ks[0][r1][cc0] = kp1;
    *(uint2*)&VTs[0][r0][cA]     = make_uint2(vp0.x, vp0.y);
    *(uint2*)&VTs[0][r0][cA + 8] = make_uint2(vp0.z, vp0.w);
    *(uint2*)&VTs[0][r1][cA]     = make_uint2(vp1.x, vp1.y);
    *(uint2*)&VTs[0][r1][cA + 8] = make_uint2(vp1.z, vp1.w);
    if (tid < 64) sb[0][tid] = (tid < nvalid) ? 0.f : -1e38f;

    kp0 = *(const uint4*)(kc + hb + (size_t)(64 + r0) * HD + cc0);
    kp1 = *(const uint4*)(kc + hb + (size_t)(64 + r1) * HD + cc0);
    vp0 = *(const uint4*)(vT + hb + (size_t)r0 * SEQ + 64 + cc0);
    vp1 = *(const uint4*)(vT + hb + (size_t)r1 * SEQ + 64 + cc0);
    float sbpre = (64 + tid < nvalid) ? 0.f : -1e38f;
    __syncthreads();

    for (int kt = 0; kt < ntiles; ++kt) {
        const int cur = kt & 1;
        if (kt < ntiles - 1) {
            *(uint4*)&Ks[cur ^ 1][r0][cc0] = kp0;
            *(uint4*)&Ks[cur ^ 1][r1][cc0] = kp1;
            *(uint2*)&VTs[cur ^ 1][r0][cA]     = make_uint2(vp0.x, vp0.y);
            *(uint2*)&VTs[cur ^ 1][r0][cA + 8] = make_uint2(vp0.z, vp0.w);
            *(uint2*)&VTs[cur ^ 1][r1][cA]     = make_uint2(vp1.x, vp1.y);
            *(uint2*)&VTs[cur ^ 1][r1][cA + 8] = make_uint2(vp1.z, vp1.w);
            if (tid < 64) sb[cur ^ 1][tid] = sbpre;
        }
        if (kt < ntiles - 2) {
            const int tn = (kt + 2) * 64;
            kp0 = *(const uint4*)(kc + hb + (size_t)(tn + r0) * HD + cc0);
            kp1 = *(const uint4*)(kc + hb + (size_t)(tn + r1) * HD + cc0);
            vp0 = *(const uint4*)(vT + hb + (size_t)r0 * SEQ + tn + cc0);
            vp1 = *(const uint4*)(vT + hb + (size_t)r1 * SEQ + tn + cc0);
            sbpre = (tn + tid < nvalid) ? 0.f : -1e38f;
        }

        // S^T = K Q^T, accumulator init = per-key mask bias (vector read)
        f32x4 sacc[2][4];
        for (int nt = 0; nt < 4; ++nt) {
            f32x4 binit = *(const f32x4*)&sb[cur][nt * 16 + 4 * h];
            sacc[0][nt] = binit;
            sacc[1][nt] = binit;
        }
        for (int dk = 0; dk < 2; ++dk) {
            for (int nt = 0; nt < 4; ++nt) {
                bf16x8 kf = *(const bf16x8*)&Ks[cur][nt * 16 + q][dk * 32 + 8 * h];
                sacc[0][nt] = MFMA(kf, qf[0][dk], sacc[0][nt]);
                sacc[1][nt] = MFMA(kf, qf[1][dk], sacc[1][nt]);
            }
        }
        // p = exp2(s^T) packed straight into PV A-fragments (in registers)
        union pk_t { bf16x8 v; __hip_bfloat16 hh[8]; } pa[2][2];
        for (int m = 0; m < 2; ++m)
            for (int kk = 0; kk < 2; ++kk)
                for (int j = 0; j < 4; ++j) {
                    pa[m][kk].hh[j]     = __float2bfloat16(exp2f(sacc[m][kk][j]));
                    pa[m][kk].hh[j + 4] = __float2bfloat16(exp2f(sacc[m][kk + 2][j]));
                }
        // acc += P @ V ; lsum += P @ ones  (V columns permuted to match)
        for (int kk = 0; kk < 2; ++kk) {
            lsum[0] = MFMA(pa[0][kk].v, ones, lsum[0]);
            lsum[1] = MFMA(pa[1][kk].v, ones, lsum[1]);
            for (int dt = 0; dt < 4; ++dt) {
                bf16x8 bv = *(const bf16x8*)&VTs[cur][dt * 16 + q][kk * 32 + 8 * h];
                acc[0][dt] = MFMA(pa[0][kk].v, bv, acc[0][dt]);
                acc[1][dt] = MFMA(pa[1][kk].v, bv, acc[1][dt]);
            }
        }
        __syncthreads();   // writes to buf[cur^1] done; reads of buf[cur] done
    }

    // lane's lsum[m][jj] IS the row-sum for acc row jj of subtile m
    for (int m = 0; m < 2; ++m) {
        float rinv[4];
        for (int jj = 0; jj < 4; ++jj) rinv[jj] = 1.f / lsum[m][jj];
        const int ibase = qt * 128 + w * 32 + m * 16 + 4 * h;
        for (int dt = 0; dt < 4; ++dt) {
            int d = dt * 16 + q;
            union { __hip_bfloat16 hh[4]; uint2 u; } o;
            for (int jj = 0; jj < 4; ++jj)
                o.hh[jj] = __float2bfloat16(acc[m][dt][jj] * rinv[jj]);
            *(uint2*)(wvt + (size_t)g * (HD * SEQ) + (size_t)d * SEQ + ibase) = o.u;
        }
    }
}

// ---------------------------------------------------------------------------
// ws layout (26MB + 18KB): Xb [0,8MB) -> aliased by wvt after QKV GEMM;
// W bf16 [8,10MB) (Wq,Wk,Wv,Wo contiguous); qb [10,18MB); kc [18,26MB);
// hdr [26MB, +18KB). vT lives in d_out's first 8 MB. kv_pad zeroes kc pad
// rows + vT pad columns every call (no stale-state reads).
// ---------------------------------------------------------------------------
extern "C" void kernel_launch(void* const* d_in, const int* in_sizes, int n_in,
                              void* d_out, int out_size, void* d_ws, size_t ws_size,
                              hipStream_t stream) {
    const float* lstm = (const float*)d_in[0];
    const int* mask = (const int*)d_in[1];
    const float* Wq = (const float*)d_in[2]; const float* bq = (const float*)d_in[3];
    const float* Wk = (const float*)d_in[4]; const float* bk = (const float*)d_in[5];
    const float* Wv = (const float*)d_in[6]; const float* bv = (const float*)d_in[7];
    const float* Wo = (const float*)d_in[8]; const float* bo = (const float*)d_in[9];
    float* out = (float*)d_out;

    const size_t NX = (size_t)MROWS * HID;    // 4M elems
    const size_t NW = (size_t)HID * HID;      // 256K elems
    __hip_bfloat16* Xb  = (__hip_bfloat16*)d_ws;            // 4M elems (8MB)
    __hip_bfloat16* Wqb = Xb + NX;                          // 256K
    __hip_bfloat16* Wkb = Wqb + NW;
    __hip_bfloat16* Wvb = Wkb + NW;
    __hip_bfloat16* Wob = Wvb + NW;
    __hip_bfloat16* qb  = Wob + NW;                         // 4M
    __hip_bfloat16* kc  = qb + NX;                          // 4M (compacted K)
    int*            hdr = (int*)(kc + NX);                  // 1 + IDXN + 2048 ints
    __hip_bfloat16* vT  = (__hip_bfloat16*)d_out;           // scratch in d_out[0,8MB)
    __hip_bfloat16* wvt = Xb;                               // alias: Xb dead after QKV GEMM

    mask_scan<<<1, 256, 0, stream>>>(mask, hdr);
    prep<<<3072, 256, 0, stream>>>(lstm, Wq, Wk, Wv, Wo, Xb, Wqb);

    dim3 gg(MROWS / 64, HID / 64), bb(256);
    gemm_qkv_fused<<<gg, bb, 0, stream>>>(Xb, Wqb, Wkb, Wvb, bq, bk, bv, hdr, qb, kc, vT);
    kv_pad<<<dim3(NG), bb, 0, stream>>>(vT, kc, hdr);
    attn<<<dim3(NG * (SEQ / 128)), bb, 0, stream>>>(qb, kc, vT, hdr, wvt);
    gemm_out<<<gg, bb, 0, stream>>>(wvt, Wob, bo, out);
}

// Round 22
// 95.481 us; speedup vs baseline: 1.0469x; 1.0469x over previous
//
#include <hip/hip_runtime.h>
#include <hip/hip_bf16.h>

// Problem constants
#define HID 512
#define SEQ 2048
#define NG 32            // (B*NUM_HEADS) after the faithful-to-source flat reshape
#define HD 64
#define MROWS 8192       // B*SEQ
#define LDP 72           // padded LDS row stride (elems) = 144B
// 1/sqrt(512) * log2(e): folded into Q so softmax is exp2(s)
#define QSC 0.0637587178f

typedef __bf16 bf16x8 __attribute__((ext_vector_type(8)));
typedef float f32x4 __attribute__((ext_vector_type(4)));

#define MFMA(a, b, c) __builtin_amdgcn_mfma_f32_16x16x32_bf16((a), (b), (c), 0, 0, 0)

// ---------------------------------------------------------------------------
// prep: merged f32->bf16 converts + mask scan.
// Blocks [0,2048): X (grid-stride). Blocks [2048,3072): weights into Wcat.
// Block 3072: mask scan -> hdr[0]=nvalid, cidx=hdr+1 (key i -> compact pos,
// -1 if masked).
// ---------------------------------------------------------------------------
__global__ __launch_bounds__(256) void prep(const float* __restrict__ X,
                                            const float* __restrict__ Wq,
                                            const float* __restrict__ Wk,
                                            const float* __restrict__ Wv,
                                            const float* __restrict__ Wo,
                                            const int* __restrict__ mask,
                                            __hip_bfloat16* __restrict__ Xb,
                                            __hip_bfloat16* __restrict__ Wc,
                                            int* __restrict__ hdr) {
    const int b = blockIdx.x;
    const int tid = threadIdx.x;
    if (b < 2048) {
        const int n4 = (MROWS * HID) / 4;
        for (int i = b * 256 + tid; i < n4; i += 2048 * 256) {
            float4 v = *(const float4*)(X + (size_t)i * 4);
            union { __hip_bfloat16 h[4]; uint2 u; } p;
            p.h[0] = __float2bfloat16(v.x); p.h[1] = __float2bfloat16(v.y);
            p.h[2] = __float2bfloat16(v.z); p.h[3] = __float2bfloat16(v.w);
            *(uint2*)(Xb + (size_t)i * 4) = p.u;
        }
    } else if (b < 3072) {
        const int wb = b - 2048;
        const int which = wb >> 8;
        const float* s = which == 0 ? Wq : (which == 1 ? Wk : (which == 2 ? Wv : Wo));
        __hip_bfloat16* o = Wc + (size_t)which * (HID * HID);
        const int i = (wb & 255) * 256 + tid;
        float4 v = *(const float4*)(s + (size_t)i * 4);
        union { __hip_bfloat16 h[4]; uint2 u; } p;
        p.h[0] = __float2bfloat16(v.x); p.h[1] = __float2bfloat16(v.y);
        p.h[2] = __float2bfloat16(v.z); p.h[3] = __float2bfloat16(v.w);
        *(uint2*)(o + (size_t)i * 4) = p.u;
    } else {
        __shared__ int s[256];
        const int base = tid * 8;
        int loc[8], cnt = 0;
        for (int j = 0; j < 8; ++j) { loc[j] = cnt; cnt += (mask[base + j] != 0); }
        s[tid] = cnt;
        __syncthreads();
        for (int off = 1; off < 256; off <<= 1) {
            int v = (tid >= off) ? s[tid - off] : 0;
            __syncthreads();
            s[tid] += v;
            __syncthreads();
        }
        const int excl = s[tid] - cnt;
        int* cidx = hdr + 1;
        for (int j = 0; j < 8; ++j) {
            int i = base + j;
            cidx[i] = (mask[i] != 0) ? (excl + loc[j]) : -1;
        }
        if (tid == 0) hdr[0] = s[255];
    }
}

// ---------------------------------------------------------------------------
// kv_pad: zero vT's pad COLUMNS [nvalid, ceil64) and kc's pad ROWS
// [nvalid, ceil64). Both hold stale bytes between replays (vT in d_out; kc's
// masked rows never written) — stale bf16 NaN would poison the accumulators
// (round-17 lesson). Round-21's clamp alternative mis-assigned V columns at
// 8-span granularity when nvalid % 8 != 0 — zeroing is the proven-safe path.
// ---------------------------------------------------------------------------
__global__ __launch_bounds__(256) void kv_pad(__hip_bfloat16* __restrict__ vT,
                                              __hip_bfloat16* __restrict__ kc,
                                              const int* __restrict__ hdr) {
    const int nvalid = hdr[0];
    const int cend = (nvalid + 63) & ~63;
    if (cend == nvalid) return;
    const int g = blockIdx.x;
    const __hip_bfloat16 z = (__hip_bfloat16)0.0f;
    for (int d = 0; d < HD; ++d)
        for (int c = nvalid + threadIdx.x; c < cend; c += 256)
            vT[(size_t)g * (HD * SEQ) + (size_t)d * SEQ + c] = z;
    const int ne = (cend - nvalid) * HD;
    __hip_bfloat16* kp = kc + ((size_t)g * SEQ + nvalid) * HD;
    for (int e = threadIdx.x; e < ne; e += 256) kp[e] = z;
}

// ---------------------------------------------------------------------------
// Fused QKV GEMM, swapped MFMA operands (vector q/k stores). BOTH k and v are
// written compacted: k rows and vT columns only for valid keys (ci >= 0), at
// their compact position. attn then reads K and V contiguously — no gather.
// ---------------------------------------------------------------------------
__global__ __launch_bounds__(256) void gemm_qkv_fused(
        const __hip_bfloat16* __restrict__ Xb,
        const __hip_bfloat16* __restrict__ Wqb, const __hip_bfloat16* __restrict__ Wkb,
        const __hip_bfloat16* __restrict__ Wvb,
        const float* __restrict__ bq, const float* __restrict__ bk, const float* __restrict__ bv,
        const int* __restrict__ hdr,
        __hip_bfloat16* __restrict__ qout, __hip_bfloat16* __restrict__ kc,
        __hip_bfloat16* __restrict__ vT) {
    __shared__ __hip_bfloat16 Xs[64][LDP];
    __shared__ __hip_bfloat16 Wqs[64][LDP];
    __shared__ __hip_bfloat16 Wks[64][LDP];
    __shared__ __hip_bfloat16 Wvs[64][LDP];
    const int tid = threadIdx.x;
    const int w = tid >> 6, l = tid & 63;
    const int h = l >> 4, q = l & 15;
    const int row0 = blockIdx.x * 64, col0 = blockIdx.y * 64;

    const int r0 = tid >> 3, r1 = (tid + 256) >> 3;
    const int cc0 = (tid & 7) * 8;
    uint4 px0, px1, pq0, pq1, pk0, pk1, pv0, pv1;
    {
        px0 = *(const uint4*)(Xb  + (size_t)(row0 + r0) * HID + cc0);
        px1 = *(const uint4*)(Xb  + (size_t)(row0 + r1) * HID + cc0);
        pq0 = *(const uint4*)(Wqb + (size_t)(col0 + r0) * HID + cc0);
        pq1 = *(const uint4*)(Wqb + (size_t)(col0 + r1) * HID + cc0);
        pk0 = *(const uint4*)(Wkb + (size_t)(col0 + r0) * HID + cc0);
        pk1 = *(const uint4*)(Wkb + (size_t)(col0 + r1) * HID + cc0);
        pv0 = *(const uint4*)(Wvb + (size_t)(col0 + r0) * HID + cc0);
        pv1 = *(const uint4*)(Wvb + (size_t)(col0 + r1) * HID + cc0);
    }

    f32x4 aq[4] = {}, ak[4] = {}, av[4] = {};
    for (int kt = 0; kt < 8; ++kt) {
        __syncthreads();
        *(uint4*)&Xs[r0][cc0]  = px0;  *(uint4*)&Xs[r1][cc0]  = px1;
        *(uint4*)&Wqs[r0][cc0] = pq0;  *(uint4*)&Wqs[r1][cc0] = pq1;
        *(uint4*)&Wks[r0][cc0] = pk0;  *(uint4*)&Wks[r1][cc0] = pk1;
        *(uint4*)&Wvs[r0][cc0] = pv0;  *(uint4*)&Wvs[r1][cc0] = pv1;
        __syncthreads();
        if (kt < 7) {
            size_t go = (size_t)(kt + 1) * 64 + cc0;
            px0 = *(const uint4*)(Xb  + (size_t)(row0 + r0) * HID + go);
            px1 = *(const uint4*)(Xb  + (size_t)(row0 + r1) * HID + go);
            pq0 = *(const uint4*)(Wqb + (size_t)(col0 + r0) * HID + go);
            pq1 = *(const uint4*)(Wqb + (size_t)(col0 + r1) * HID + go);
            pk0 = *(const uint4*)(Wkb + (size_t)(col0 + r0) * HID + go);
            pk1 = *(const uint4*)(Wkb + (size_t)(col0 + r1) * HID + go);
            pv0 = *(const uint4*)(Wvb + (size_t)(col0 + r0) * HID + go);
            pv1 = *(const uint4*)(Wvb + (size_t)(col0 + r1) * HID + go);
        }
        for (int dk = 0; dk < 2; ++dk) {
            bf16x8 x = *(const bf16x8*)&Xs[w * 16 + q][dk * 32 + 8 * h];
            for (int nt = 0; nt < 4; ++nt) {
                int rr = nt * 16 + q, cc = dk * 32 + 8 * h;
                aq[nt] = MFMA(*(const bf16x8*)&Wqs[rr][cc], x, aq[nt]);
                ak[nt] = MFMA(*(const bf16x8*)&Wks[rr][cc], x, ak[nt]);
                av[nt] = MFMA(*(const bf16x8*)&Wvs[rr][cc], x, av[nt]);
            }
        }
    }
    // epilogue: lane row m = row0 + w*16 + q; cols n = col0 + nt*16 + 4h + jj
    const int m = row0 + w * 16 + q;
    const int g = row0 >> 8;
    const int irow = ((m & 255) << 3) + (int)blockIdx.y;   // key index i
    const int ci = hdr[1 + irow];                          // compact pos (-1 = masked)
    for (int nt = 0; nt < 4; ++nt) {
        int nb = col0 + nt * 16 + 4 * h;
        float4 b4q = *(const float4*)(bq + nb);
        float4 b4k = *(const float4*)(bk + nb);
        float4 b4v = *(const float4*)(bv + nb);
        const float* bqf = (const float*)&b4q;
        const float* bkf = (const float*)&b4k;
        const float* bvf = (const float*)&b4v;
        union { __hip_bfloat16 hh[4]; uint2 u; } oq, ok;
        for (int jj = 0; jj < 4; ++jj) {
            oq.hh[jj] = __float2bfloat16((aq[nt][jj] + bqf[jj]) * QSC);
            ok.hh[jj] = __float2bfloat16(ak[nt][jj] + bkf[jj]);
        }
        *(uint2*)(qout + (size_t)m * HID + nb) = oq.u;
        if (ci >= 0) {
            int db = nb & 63;   // col0 is a multiple of 64
            *(uint2*)(kc + ((size_t)g * SEQ + ci) * HD + db) = ok.u;
            for (int jj = 0; jj < 4; ++jj)
                vT[(size_t)g * (HD * SEQ) + (size_t)(db + jj) * SEQ + ci] =
                    __float2bfloat16(av[nt][jj] + bvf[jj]);
        }
    }
}

// ---------------------------------------------------------------------------
// GEMM: out_f32[M x 512] = X_bf16 @ Wo_bf16^T + bo. Swapped operands ->
// float4 (16B) contiguous output stores.
// ---------------------------------------------------------------------------
__global__ __launch_bounds__(256) void gemm_out(const __hip_bfloat16* __restrict__ X,
                                                const __hip_bfloat16* __restrict__ W,
                                                const float* __restrict__ bias,
                                                float* __restrict__ out) {
    __shared__ __hip_bfloat16 Xs[64][LDP];
    __shared__ __hip_bfloat16 Ws[64][LDP];
    const int tid = threadIdx.x;
    const int w = tid >> 6, l = tid & 63;
    const int h = l >> 4, q = l & 15;
    const int row0 = blockIdx.x * 64, col0 = blockIdx.y * 64;

    const int r0 = tid >> 3, r1 = (tid + 256) >> 3;
    const int cc0 = (tid & 7) * 8;
    uint4 px0 = *(const uint4*)(X + (size_t)(row0 + r0) * HID + cc0);
    uint4 px1 = *(const uint4*)(X + (size_t)(row0 + r1) * HID + cc0);
    uint4 pw0 = *(const uint4*)(W + (size_t)(col0 + r0) * HID + cc0);
    uint4 pw1 = *(const uint4*)(W + (size_t)(col0 + r1) * HID + cc0);

    f32x4 acc[4] = {};
    for (int kt = 0; kt < 8; ++kt) {
        __syncthreads();
        *(uint4*)&Xs[r0][cc0] = px0;  *(uint4*)&Xs[r1][cc0] = px1;
        *(uint4*)&Ws[r0][cc0] = pw0;  *(uint4*)&Ws[r1][cc0] = pw1;
        __syncthreads();
        if (kt < 7) {
            size_t go = (size_t)(kt + 1) * 64 + cc0;
            px0 = *(const uint4*)(X + (size_t)(row0 + r0) * HID + go);
            px1 = *(const uint4*)(X + (size_t)(row0 + r1) * HID + go);
            pw0 = *(const uint4*)(W + (size_t)(col0 + r0) * HID + go);
            pw1 = *(const uint4*)(W + (size_t)(col0 + r1) * HID + go);
        }
        for (int dk = 0; dk < 2; ++dk) {
            bf16x8 x = *(const bf16x8*)&Xs[w * 16 + q][dk * 32 + 8 * h];
            for (int nt = 0; nt < 4; ++nt) {
                bf16x8 b = *(const bf16x8*)&Ws[nt * 16 + q][dk * 32 + 8 * h];
                acc[nt] = MFMA(b, x, acc[nt]);
            }
        }
    }
    const int m = row0 + w * 16 + q;
    for (int nt = 0; nt < 4; ++nt) {
        int nb = col0 + nt * 16 + 4 * h;
        float4 b4 = *(const float4*)(bias + nb);
        float4 o = make_float4(acc[nt][0] + b4.x, acc[nt][1] + b4.y,
                               acc[nt][2] + b4.z, acc[nt][3] + b4.w);
        *(float4*)(out + (size_t)m * HID + nb) = o;
    }
}

// ---------------------------------------------------------------------------
// Attention over COMPACTED keys, ntiles = ceil(nvalid/64). K and V staged
// contiguously (pads zeroed by kv_pad; tail keys masked via sbias).
// Swapped-QK^T in-register softmax; row-sums via all-ones MFMA.
// ---------------------------------------------------------------------------
__global__ __launch_bounds__(256) void attn(const __hip_bfloat16* __restrict__ qg,
                                            const __hip_bfloat16* __restrict__ kc,
                                            const __hip_bfloat16* __restrict__ vT,
                                            const int* __restrict__ hdr,
                                            __hip_bfloat16* __restrict__ wvt) {
    __shared__ __hip_bfloat16 Ks[2][64][LDP];
    __shared__ __hip_bfloat16 VTs[2][64][LDP];
    __shared__ float sb[2][64];

    const int tid = threadIdx.x;
    const int w = tid >> 6, l = tid & 63;
    const int h = l >> 4, q = l & 15;
    // XCD-chunked swizzle: 512 blocks % 8 == 0 -> bijective
    const int bid = (blockIdx.x & 7) * 64 + (blockIdx.x >> 3);
    const int g = bid >> 4, qt = bid & 15;
    const size_t hb = (size_t)g * (SEQ * HD);

    const int nvalid = hdr[0];
    const int ntiles = (nvalid + 63) >> 6;

    // Q fragments in registers (one-time global read, L2-resident)
    bf16x8 qf[2][2];
    for (int m = 0; m < 2; ++m)
        for (int dk = 0; dk < 2; ++dk)
            qf[m][dk] = *(const bf16x8*)(qg + hb +
                (size_t)(qt * 128 + w * 32 + m * 16 + q) * HD + dk * 32 + 8 * h);

    const int r0 = tid >> 3, r1 = (tid + 256) >> 3;
    const int cc0 = (tid & 7) * 8;
    // permuted V dest base: keys cc0..cc0+3 -> cA..cA+3, cc0+4..+7 -> cA+8..+11
    const int ntc = cc0 >> 4;
    const int cA = (ntc & 1) * 32 + ((cc0 >> 2) & 3) * 8 + (ntc >> 1) * 4;

    const __bf16 kOne = (__bf16)1.0f;
    const bf16x8 ones = {kOne, kOne, kOne, kOne, kOne, kOne, kOne, kOne};

    f32x4 acc[2][4] = {};
    f32x4 lsum[2] = {};

    // ---- prologue: tile 0 into buf 0; tile 1 into regs ----
    uint4 kp0 = *(const uint4*)(kc + hb + (size_t)r0 * HD + cc0);
    uint4 kp1 = *(const uint4*)(kc + hb + (size_t)r1 * HD + cc0);
    uint4 vp0 = *(const uint4*)(vT + hb + (size_t)r0 * SEQ + cc0);
    uint4 vp1 = *(const uint4*)(vT + hb + (size_t)r1 * SEQ + cc0);

    *(uint4*)&Ks[0][r0][cc0] = kp0;
    *(uint4*)&Ks[0][r1][cc0] = kp1;
    *(uint2*)&VTs[0][r0][cA]     = make_uint2(vp0.x, vp0.y);
    *(uint2*)&VTs[0][r0][cA + 8] = make_uint2(vp0.z, vp0.w);
    *(uint2*)&VTs[0][r1][cA]     = make_uint2(vp1.x, vp1.y);
    *(uint2*)&VTs[0][r1][cA + 8] = make_uint2(vp1.z, vp1.w);
    if (tid < 64) sb[0][tid] = (tid < nvalid) ? 0.f : -1e38f;

    kp0 = *(const uint4*)(kc + hb + (size_t)(64 + r0) * HD + cc0);
    kp1 = *(const uint4*)(kc + hb + (size_t)(64 + r1) * HD + cc0);
    vp0 = *(const uint4*)(vT + hb + (size_t)r0 * SEQ + 64 + cc0);
    vp1 = *(const uint4*)(vT + hb + (size_t)r1 * SEQ + 64 + cc0);
    float sbpre = (64 + tid < nvalid) ? 0.f : -1e38f;
    __syncthreads();

    for (int kt = 0; kt < ntiles; ++kt) {
        const int cur = kt & 1;
        if (kt < ntiles - 1) {
            *(uint4*)&Ks[cur ^ 1][r0][cc0] = kp0;
            *(uint4*)&Ks[cur ^ 1][r1][cc0] = kp1;
            *(uint2*)&VTs[cur ^ 1][r0][cA]     = make_uint2(vp0.x, vp0.y);
            *(uint2*)&VTs[cur ^ 1][r0][cA + 8] = make_uint2(vp0.z, vp0.w);
            *(uint2*)&VTs[cur ^ 1][r1][cA]     = make_uint2(vp1.x, vp1.y);
            *(uint2*)&VTs[cur ^ 1][r1][cA + 8] = make_uint2(vp1.z, vp1.w);
            if (tid < 64) sb[cur ^ 1][tid] = sbpre;
        }
        if (kt < ntiles - 2) {
            const int tn = (kt + 2) * 64;
            kp0 = *(const uint4*)(kc + hb + (size_t)(tn + r0) * HD + cc0);
            kp1 = *(const uint4*)(kc + hb + (size_t)(tn + r1) * HD + cc0);
            vp0 = *(const uint4*)(vT + hb + (size_t)r0 * SEQ + tn + cc0);
            vp1 = *(const uint4*)(vT + hb + (size_t)r1 * SEQ + tn + cc0);
            sbpre = (tn + tid < nvalid) ? 0.f : -1e38f;
        }

        // S^T = K Q^T, accumulator init = per-key mask bias (vector read)
        f32x4 sacc[2][4];
        for (int nt = 0; nt < 4; ++nt) {
            f32x4 binit = *(const f32x4*)&sb[cur][nt * 16 + 4 * h];
            sacc[0][nt] = binit;
            sacc[1][nt] = binit;
        }
        for (int dk = 0; dk < 2; ++dk) {
            for (int nt = 0; nt < 4; ++nt) {
                bf16x8 kf = *(const bf16x8*)&Ks[cur][nt * 16 + q][dk * 32 + 8 * h];
                sacc[0][nt] = MFMA(kf, qf[0][dk], sacc[0][nt]);
                sacc[1][nt] = MFMA(kf, qf[1][dk], sacc[1][nt]);
            }
        }
        // p = exp2(s^T) packed straight into PV A-fragments (in registers)
        union pk_t { bf16x8 v; __hip_bfloat16 hh[8]; } pa[2][2];
        for (int m = 0; m < 2; ++m)
            for (int kk = 0; kk < 2; ++kk)
                for (int j = 0; j < 4; ++j) {
                    pa[m][kk].hh[j]     = __float2bfloat16(exp2f(sacc[m][kk][j]));
                    pa[m][kk].hh[j + 4] = __float2bfloat16(exp2f(sacc[m][kk + 2][j]));
                }
        // acc += P @ V ; lsum += P @ ones  (V columns permuted to match)
        for (int kk = 0; kk < 2; ++kk) {
            lsum[0] = MFMA(pa[0][kk].v, ones, lsum[0]);
            lsum[1] = MFMA(pa[1][kk].v, ones, lsum[1]);
            for (int dt = 0; dt < 4; ++dt) {
                bf16x8 bv = *(const bf16x8*)&VTs[cur][dt * 16 + q][kk * 32 + 8 * h];
                acc[0][dt] = MFMA(pa[0][kk].v, bv, acc[0][dt]);
                acc[1][dt] = MFMA(pa[1][kk].v, bv, acc[1][dt]);
            }
        }
        __syncthreads();   // writes to buf[cur^1] done; reads of buf[cur] done
    }

    // lane's lsum[m][jj] IS the row-sum for acc row jj of subtile m
    for (int m = 0; m < 2; ++m) {
        float rinv[4];
        for (int jj = 0; jj < 4; ++jj) rinv[jj] = 1.f / lsum[m][jj];
        const int ibase = qt * 128 + w * 32 + m * 16 + 4 * h;
        for (int dt = 0; dt < 4; ++dt) {
            int d = dt * 16 + q;
            union { __hip_bfloat16 hh[4]; uint2 u; } o;
            for (int jj = 0; jj < 4; ++jj)
                o.hh[jj] = __float2bfloat16(acc[m][dt][jj] * rinv[jj]);
            *(uint2*)(wvt + (size_t)g * (HD * SEQ) + (size_t)d * SEQ + ibase) = o.u;
        }
    }
}

// ---------------------------------------------------------------------------
// ws layout (26MB + 8.2KB): Xb [0,8MB) -> aliased by wvt after QKV GEMM;
// W bf16 [8,10MB) (Wq,Wk,Wv,Wo contiguous); qb [10,18MB); kc [18,26MB);
// hdr [26MB, +8.2KB) = {nvalid, cidx[2048]}. vT lives in d_out's first 8 MB.
// kv_pad zeroes kc pad rows + vT pad columns every call.
// ---------------------------------------------------------------------------
extern "C" void kernel_launch(void* const* d_in, const int* in_sizes, int n_in,
                              void* d_out, int out_size, void* d_ws, size_t ws_size,
                              hipStream_t stream) {
    const float* lstm = (const float*)d_in[0];
    const int* mask = (const int*)d_in[1];
    const float* Wq = (const float*)d_in[2]; const float* bq = (const float*)d_in[3];
    const float* Wk = (const float*)d_in[4]; const float* bk = (const float*)d_in[5];
    const float* Wv = (const float*)d_in[6]; const float* bv = (const float*)d_in[7];
    const float* Wo = (const float*)d_in[8]; const float* bo = (const float*)d_in[9];
    float* out = (float*)d_out;

    const size_t NX = (size_t)MROWS * HID;    // 4M elems
    const size_t NW = (size_t)HID * HID;      // 256K elems
    __hip_bfloat16* Xb  = (__hip_bfloat16*)d_ws;            // 4M elems (8MB)
    __hip_bfloat16* Wqb = Xb + NX;                          // 256K
    __hip_bfloat16* Wkb = Wqb + NW;
    __hip_bfloat16* Wvb = Wkb + NW;
    __hip_bfloat16* Wob = Wvb + NW;
    __hip_bfloat16* qb  = Wob + NW;                         // 4M
    __hip_bfloat16* kc  = qb + NX;                          // 4M (compacted K)
    int*            hdr = (int*)(kc + NX);                  // 1 + 2048 ints
    __hip_bfloat16* vT  = (__hip_bfloat16*)d_out;           // scratch in d_out[0,8MB)
    __hip_bfloat16* wvt = Xb;                               // alias: Xb dead after QKV GEMM

    prep<<<3073, 256, 0, stream>>>(lstm, Wq, Wk, Wv, Wo, mask, Xb, Wqb, hdr);

    dim3 gg(MROWS / 64, HID / 64), bb(256);
    gemm_qkv_fused<<<gg, bb, 0, stream>>>(Xb, Wqb, Wkb, Wvb, bq, bk, bv, hdr, qb, kc, vT);
    kv_pad<<<dim3(NG), bb, 0, stream>>>(vT, kc, hdr);
    attn<<<dim3(NG * (SEQ / 128)), bb, 0, stream>>>(qb, kc, vT, hdr, wvt);
    gemm_out<<<gg, bb, 0, stream>>>(wvt, Wob, bo, out);
}

// Round 23
// 88.842 us; speedup vs baseline: 1.1251x; 1.0747x over previous
//
#include <hip/hip_runtime.h>
#include <hip/hip_bf16.h>

// Problem constants
#define HID 512
#define SEQ 2048
#define NG 32            // (B*NUM_HEADS) after the faithful-to-source flat reshape
#define HD 64
#define MROWS 8192       // B*SEQ
#define LDP 72           // padded LDS row stride (elems) = 144B
// 1/sqrt(512) * log2(e): folded into Q so softmax is exp2(s)
#define QSC 0.0637587178f

typedef __bf16 bf16x8 __attribute__((ext_vector_type(8)));
typedef float f32x4 __attribute__((ext_vector_type(4)));

#define MFMA(a, b, c) __builtin_amdgcn_mfma_f32_16x16x32_bf16((a), (b), (c), 0, 0, 0)

// ---------------------------------------------------------------------------
// prep: merged f32->bf16 converts + mask scan.
// Blocks [0,2048): X (grid-stride). Blocks [2048,3072): weights into Wcat.
// Block 3072: mask scan -> hdr[0]=nvalid, cidx=hdr+1 (key i -> compact pos,
// -1 if masked).
// ---------------------------------------------------------------------------
__global__ __launch_bounds__(256) void prep(const float* __restrict__ X,
                                            const float* __restrict__ Wq,
                                            const float* __restrict__ Wk,
                                            const float* __restrict__ Wv,
                                            const float* __restrict__ Wo,
                                            const int* __restrict__ mask,
                                            __hip_bfloat16* __restrict__ Xb,
                                            __hip_bfloat16* __restrict__ Wc,
                                            int* __restrict__ hdr) {
    const int b = blockIdx.x;
    const int tid = threadIdx.x;
    if (b < 2048) {
        const int n4 = (MROWS * HID) / 4;
        for (int i = b * 256 + tid; i < n4; i += 2048 * 256) {
            float4 v = *(const float4*)(X + (size_t)i * 4);
            union { __hip_bfloat16 h[4]; uint2 u; } p;
            p.h[0] = __float2bfloat16(v.x); p.h[1] = __float2bfloat16(v.y);
            p.h[2] = __float2bfloat16(v.z); p.h[3] = __float2bfloat16(v.w);
            *(uint2*)(Xb + (size_t)i * 4) = p.u;
        }
    } else if (b < 3072) {
        const int wb = b - 2048;
        const int which = wb >> 8;
        const float* s = which == 0 ? Wq : (which == 1 ? Wk : (which == 2 ? Wv : Wo));
        __hip_bfloat16* o = Wc + (size_t)which * (HID * HID);
        const int i = (wb & 255) * 256 + tid;
        float4 v = *(const float4*)(s + (size_t)i * 4);
        union { __hip_bfloat16 h[4]; uint2 u; } p;
        p.h[0] = __float2bfloat16(v.x); p.h[1] = __float2bfloat16(v.y);
        p.h[2] = __float2bfloat16(v.z); p.h[3] = __float2bfloat16(v.w);
        *(uint2*)(o + (size_t)i * 4) = p.u;
    } else {
        __shared__ int s[256];
        const int base = tid * 8;
        int loc[8], cnt = 0;
        for (int j = 0; j < 8; ++j) { loc[j] = cnt; cnt += (mask[base + j] != 0); }
        s[tid] = cnt;
        __syncthreads();
        for (int off = 1; off < 256; off <<= 1) {
            int v = (tid >= off) ? s[tid - off] : 0;
            __syncthreads();
            s[tid] += v;
            __syncthreads();
        }
        const int excl = s[tid] - cnt;
        int* cidx = hdr + 1;
        for (int j = 0; j < 8; ++j) {
            int i = base + j;
            cidx[i] = (mask[i] != 0) ? (excl + loc[j]) : -1;
        }
        if (tid == 0) hdr[0] = s[255];
    }
}

// ---------------------------------------------------------------------------
// Fused QKV GEMM, swapped MFMA operands (vector q/k stores). BOTH k and v are
// written compacted: k rows and vT columns only for valid keys (ci >= 0), at
// their compact position. attn then reads K and V contiguously — no gather.
// ---------------------------------------------------------------------------
__global__ __launch_bounds__(256) void gemm_qkv_fused(
        const __hip_bfloat16* __restrict__ Xb,
        const __hip_bfloat16* __restrict__ Wqb, const __hip_bfloat16* __restrict__ Wkb,
        const __hip_bfloat16* __restrict__ Wvb,
        const float* __restrict__ bq, const float* __restrict__ bk, const float* __restrict__ bv,
        const int* __restrict__ hdr,
        __hip_bfloat16* __restrict__ qout, __hip_bfloat16* __restrict__ kc,
        __hip_bfloat16* __restrict__ vT) {
    __shared__ __hip_bfloat16 Xs[64][LDP];
    __shared__ __hip_bfloat16 Wqs[64][LDP];
    __shared__ __hip_bfloat16 Wks[64][LDP];
    __shared__ __hip_bfloat16 Wvs[64][LDP];
    const int tid = threadIdx.x;
    const int w = tid >> 6, l = tid & 63;
    const int h = l >> 4, q = l & 15;
    const int row0 = blockIdx.x * 64, col0 = blockIdx.y * 64;

    const int r0 = tid >> 3, r1 = (tid + 256) >> 3;
    const int cc0 = (tid & 7) * 8;
    uint4 px0, px1, pq0, pq1, pk0, pk1, pv0, pv1;
    {
        px0 = *(const uint4*)(Xb  + (size_t)(row0 + r0) * HID + cc0);
        px1 = *(const uint4*)(Xb  + (size_t)(row0 + r1) * HID + cc0);
        pq0 = *(const uint4*)(Wqb + (size_t)(col0 + r0) * HID + cc0);
        pq1 = *(const uint4*)(Wqb + (size_t)(col0 + r1) * HID + cc0);
        pk0 = *(const uint4*)(Wkb + (size_t)(col0 + r0) * HID + cc0);
        pk1 = *(const uint4*)(Wkb + (size_t)(col0 + r1) * HID + cc0);
        pv0 = *(const uint4*)(Wvb + (size_t)(col0 + r0) * HID + cc0);
        pv1 = *(const uint4*)(Wvb + (size_t)(col0 + r1) * HID + cc0);
    }

    f32x4 aq[4] = {}, ak[4] = {}, av[4] = {};
    for (int kt = 0; kt < 8; ++kt) {
        __syncthreads();
        *(uint4*)&Xs[r0][cc0]  = px0;  *(uint4*)&Xs[r1][cc0]  = px1;
        *(uint4*)&Wqs[r0][cc0] = pq0;  *(uint4*)&Wqs[r1][cc0] = pq1;
        *(uint4*)&Wks[r0][cc0] = pk0;  *(uint4*)&Wks[r1][cc0] = pk1;
        *(uint4*)&Wvs[r0][cc0] = pv0;  *(uint4*)&Wvs[r1][cc0] = pv1;
        __syncthreads();
        if (kt < 7) {
            size_t go = (size_t)(kt + 1) * 64 + cc0;
            px0 = *(const uint4*)(Xb  + (size_t)(row0 + r0) * HID + go);
            px1 = *(const uint4*)(Xb  + (size_t)(row0 + r1) * HID + go);
            pq0 = *(const uint4*)(Wqb + (size_t)(col0 + r0) * HID + go);
            pq1 = *(const uint4*)(Wqb + (size_t)(col0 + r1) * HID + go);
            pk0 = *(const uint4*)(Wkb + (size_t)(col0 + r0) * HID + go);
            pk1 = *(const uint4*)(Wkb + (size_t)(col0 + r1) * HID + go);
            pv0 = *(const uint4*)(Wvb + (size_t)(col0 + r0) * HID + go);
            pv1 = *(const uint4*)(Wvb + (size_t)(col0 + r1) * HID + go);
        }
        for (int dk = 0; dk < 2; ++dk) {
            bf16x8 x = *(const bf16x8*)&Xs[w * 16 + q][dk * 32 + 8 * h];
            for (int nt = 0; nt < 4; ++nt) {
                int rr = nt * 16 + q, cc = dk * 32 + 8 * h;
                aq[nt] = MFMA(*(const bf16x8*)&Wqs[rr][cc], x, aq[nt]);
                ak[nt] = MFMA(*(const bf16x8*)&Wks[rr][cc], x, ak[nt]);
                av[nt] = MFMA(*(const bf16x8*)&Wvs[rr][cc], x, av[nt]);
            }
        }
    }
    // epilogue: lane row m = row0 + w*16 + q; cols n = col0 + nt*16 + 4h + jj
    const int m = row0 + w * 16 + q;
    const int g = row0 >> 8;
    const int irow = ((m & 255) << 3) + (int)blockIdx.y;   // key index i
    const int ci = hdr[1 + irow];                          // compact pos (-1 = masked)
    for (int nt = 0; nt < 4; ++nt) {
        int nb = col0 + nt * 16 + 4 * h;
        float4 b4q = *(const float4*)(bq + nb);
        float4 b4k = *(const float4*)(bk + nb);
        float4 b4v = *(const float4*)(bv + nb);
        const float* bqf = (const float*)&b4q;
        const float* bkf = (const float*)&b4k;
        const float* bvf = (const float*)&b4v;
        union { __hip_bfloat16 hh[4]; uint2 u; } oq, ok;
        for (int jj = 0; jj < 4; ++jj) {
            oq.hh[jj] = __float2bfloat16((aq[nt][jj] + bqf[jj]) * QSC);
            ok.hh[jj] = __float2bfloat16(ak[nt][jj] + bkf[jj]);
        }
        *(uint2*)(qout + (size_t)m * HID + nb) = oq.u;
        if (ci >= 0) {
            int db = nb & 63;   // col0 is a multiple of 64
            *(uint2*)(kc + ((size_t)g * SEQ + ci) * HD + db) = ok.u;
            for (int jj = 0; jj < 4; ++jj)
                vT[(size_t)g * (HD * SEQ) + (size_t)(db + jj) * SEQ + ci] =
                    __float2bfloat16(av[nt][jj] + bvf[jj]);
        }
    }
}

// ---------------------------------------------------------------------------
// GEMM: out_f32[M x 512] = X_bf16 @ Wo_bf16^T + bo. Swapped operands ->
// float4 (16B) contiguous output stores.
// ---------------------------------------------------------------------------
__global__ __launch_bounds__(256) void gemm_out(const __hip_bfloat16* __restrict__ X,
                                                const __hip_bfloat16* __restrict__ W,
                                                const float* __restrict__ bias,
                                                float* __restrict__ out) {
    __shared__ __hip_bfloat16 Xs[64][LDP];
    __shared__ __hip_bfloat16 Ws[64][LDP];
    const int tid = threadIdx.x;
    const int w = tid >> 6, l = tid & 63;
    const int h = l >> 4, q = l & 15;
    const int row0 = blockIdx.x * 64, col0 = blockIdx.y * 64;

    const int r0 = tid >> 3, r1 = (tid + 256) >> 3;
    const int cc0 = (tid & 7) * 8;
    uint4 px0 = *(const uint4*)(X + (size_t)(row0 + r0) * HID + cc0);
    uint4 px1 = *(const uint4*)(X + (size_t)(row0 + r1) * HID + cc0);
    uint4 pw0 = *(const uint4*)(W + (size_t)(col0 + r0) * HID + cc0);
    uint4 pw1 = *(const uint4*)(W + (size_t)(col0 + r1) * HID + cc0);

    f32x4 acc[4] = {};
    for (int kt = 0; kt < 8; ++kt) {
        __syncthreads();
        *(uint4*)&Xs[r0][cc0] = px0;  *(uint4*)&Xs[r1][cc0] = px1;
        *(uint4*)&Ws[r0][cc0] = pw0;  *(uint4*)&Ws[r1][cc0] = pw1;
        __syncthreads();
        if (kt < 7) {
            size_t go = (size_t)(kt + 1) * 64 + cc0;
            px0 = *(const uint4*)(X + (size_t)(row0 + r0) * HID + go);
            px1 = *(const uint4*)(X + (size_t)(row0 + r1) * HID + go);
            pw0 = *(const uint4*)(W + (size_t)(col0 + r0) * HID + go);
            pw1 = *(const uint4*)(W + (size_t)(col0 + r1) * HID + go);
        }
        for (int dk = 0; dk < 2; ++dk) {
            bf16x8 x = *(const bf16x8*)&Xs[w * 16 + q][dk * 32 + 8 * h];
            for (int nt = 0; nt < 4; ++nt) {
                bf16x8 b = *(const bf16x8*)&Ws[nt * 16 + q][dk * 32 + 8 * h];
                acc[nt] = MFMA(b, x, acc[nt]);
            }
        }
    }
    const int m = row0 + w * 16 + q;
    for (int nt = 0; nt < 4; ++nt) {
        int nb = col0 + nt * 16 + 4 * h;
        float4 b4 = *(const float4*)(bias + nb);
        float4 o = make_float4(acc[nt][0] + b4.x, acc[nt][1] + b4.y,
                               acc[nt][2] + b4.z, acc[nt][3] + b4.w);
        *(float4*)(out + (size_t)m * HID + nb) = o;
    }
}

// ---------------------------------------------------------------------------
// Tail sanitizers (replace the kv_pad kernel). Stale replay bytes in the pad
// region could be bf16 NaN; pads only need FINITE values (sbias gives them
// p = 0, and 0 * finite = 0 exactly). Granularity is the round-21 lesson:
//   K: row-granular (whole row valid or pad),
//   V: ELEMENT-granular (a boundary 8-key span mixes valid + pad keys).
// Selects act on the loaded register — stale data never enters arithmetic,
// and all addresses stay in-bounds, so no pre-zeroing pass is needed.
// ---------------------------------------------------------------------------
__device__ __forceinline__ uint4 ktail(uint4 v, int row, int nvalid) {
    return (row < nvalid) ? v : uint4{0u, 0u, 0u, 0u};
}
__device__ __forceinline__ uint4 vtail(uint4 v, int kbase, int nvalid) {
    union { uint4 u; __hip_bfloat16 hh[8]; } t;
    t.u = v;
    for (int j = 0; j < 8; ++j)
        if (kbase + j >= nvalid) t.hh[j] = (__hip_bfloat16)0.0f;
    return t.u;
}

// ---------------------------------------------------------------------------
// Attention over COMPACTED keys, ntiles = ceil(nvalid/64). K and V staged
// contiguously; the tail tile is sanitized in-register (ktail/vtail) and its
// keys masked via sbias. Swapped-QK^T in-register softmax; row-sums via
// all-ones MFMA.
// ---------------------------------------------------------------------------
__global__ __launch_bounds__(256) void attn(const __hip_bfloat16* __restrict__ qg,
                                            const __hip_bfloat16* __restrict__ kc,
                                            const __hip_bfloat16* __restrict__ vT,
                                            const int* __restrict__ hdr,
                                            __hip_bfloat16* __restrict__ wvt) {
    __shared__ __hip_bfloat16 Ks[2][64][LDP];
    __shared__ __hip_bfloat16 VTs[2][64][LDP];
    __shared__ float sb[2][64];

    const int tid = threadIdx.x;
    const int w = tid >> 6, l = tid & 63;
    const int h = l >> 4, q = l & 15;
    // XCD-chunked swizzle: 512 blocks % 8 == 0 -> bijective
    const int bid = (blockIdx.x & 7) * 64 + (blockIdx.x >> 3);
    const int g = bid >> 4, qt = bid & 15;
    const size_t hb = (size_t)g * (SEQ * HD);

    const int nvalid = hdr[0];
    const int ntiles = (nvalid + 63) >> 6;

    // Q fragments in registers (one-time global read, L2-resident)
    bf16x8 qf[2][2];
    for (int m = 0; m < 2; ++m)
        for (int dk = 0; dk < 2; ++dk)
            qf[m][dk] = *(const bf16x8*)(qg + hb +
                (size_t)(qt * 128 + w * 32 + m * 16 + q) * HD + dk * 32 + 8 * h);

    const int r0 = tid >> 3, r1 = (tid + 256) >> 3;
    const int cc0 = (tid & 7) * 8;
    // permuted V dest base: keys cc0..cc0+3 -> cA..cA+3, cc0+4..+7 -> cA+8..+11
    const int ntc = cc0 >> 4;
    const int cA = (ntc & 1) * 32 + ((cc0 >> 2) & 3) * 8 + (ntc >> 1) * 4;

    const __bf16 kOne = (__bf16)1.0f;
    const bf16x8 ones = {kOne, kOne, kOne, kOne, kOne, kOne, kOne, kOne};

    f32x4 acc[2][4] = {};
    f32x4 lsum[2] = {};

    // ---- prologue: tile 0 into buf 0; tile 1 into regs ----
    uint4 kp0 = *(const uint4*)(kc + hb + (size_t)r0 * HD + cc0);
    uint4 kp1 = *(const uint4*)(kc + hb + (size_t)r1 * HD + cc0);
    uint4 vp0 = *(const uint4*)(vT + hb + (size_t)r0 * SEQ + cc0);
    uint4 vp1 = *(const uint4*)(vT + hb + (size_t)r1 * SEQ + cc0);
    if (ntiles == 1) {          // tile 0 is the tail
        kp0 = ktail(kp0, r0, nvalid);
        kp1 = ktail(kp1, r1, nvalid);
        vp0 = vtail(vp0, cc0, nvalid);
        vp1 = vtail(vp1, cc0, nvalid);
    }

    *(uint4*)&Ks[0][r0][cc0] = kp0;
    *(uint4*)&Ks[0][r1][cc0] = kp1;
    *(uint2*)&VTs[0][r0][cA]     = make_uint2(vp0.x, vp0.y);
    *(uint2*)&VTs[0][r0][cA + 8] = make_uint2(vp0.z, vp0.w);
    *(uint2*)&VTs[0][r1][cA]     = make_uint2(vp1.x, vp1.y);
    *(uint2*)&VTs[0][r1][cA + 8] = make_uint2(vp1.z, vp1.w);
    if (tid < 64) sb[0][tid] = (tid < nvalid) ? 0.f : -1e38f;

    kp0 = *(const uint4*)(kc + hb + (size_t)(64 + r0) * HD + cc0);
    kp1 = *(const uint4*)(kc + hb + (size_t)(64 + r1) * HD + cc0);
    vp0 = *(const uint4*)(vT + hb + (size_t)r0 * SEQ + 64 + cc0);
    vp1 = *(const uint4*)(vT + hb + (size_t)r1 * SEQ + 64 + cc0);
    if (ntiles == 2) {          // tile 1 is the tail
        kp0 = ktail(kp0, 64 + r0, nvalid);
        kp1 = ktail(kp1, 64 + r1, nvalid);
        vp0 = vtail(vp0, 64 + cc0, nvalid);
        vp1 = vtail(vp1, 64 + cc0, nvalid);
    }
    float sbpre = (64 + tid < nvalid) ? 0.f : -1e38f;
    __syncthreads();

    for (int kt = 0; kt < ntiles; ++kt) {
        const int cur = kt & 1;
        if (kt < ntiles - 1) {
            *(uint4*)&Ks[cur ^ 1][r0][cc0] = kp0;
            *(uint4*)&Ks[cur ^ 1][r1][cc0] = kp1;
            *(uint2*)&VTs[cur ^ 1][r0][cA]     = make_uint2(vp0.x, vp0.y);
            *(uint2*)&VTs[cur ^ 1][r0][cA + 8] = make_uint2(vp0.z, vp0.w);
            *(uint2*)&VTs[cur ^ 1][r1][cA]     = make_uint2(vp1.x, vp1.y);
            *(uint2*)&VTs[cur ^ 1][r1][cA + 8] = make_uint2(vp1.z, vp1.w);
            if (tid < 64) sb[cur ^ 1][tid] = sbpre;
        }
        if (kt < ntiles - 2) {
            const int tn = (kt + 2) * 64;
            kp0 = *(const uint4*)(kc + hb + (size_t)(tn + r0) * HD + cc0);
            kp1 = *(const uint4*)(kc + hb + (size_t)(tn + r1) * HD + cc0);
            vp0 = *(const uint4*)(vT + hb + (size_t)r0 * SEQ + tn + cc0);
            vp1 = *(const uint4*)(vT + hb + (size_t)r1 * SEQ + tn + cc0);
            if (kt + 2 == ntiles - 1) {   // prefetched tile is the tail
                kp0 = ktail(kp0, tn + r0, nvalid);
                kp1 = ktail(kp1, tn + r1, nvalid);
                vp0 = vtail(vp0, tn + cc0, nvalid);
                vp1 = vtail(vp1, tn + cc0, nvalid);
            }
            sbpre = (tn + tid < nvalid) ? 0.f : -1e38f;
        }

        // S^T = K Q^T, accumulator init = per-key mask bias (vector read)
        f32x4 sacc[2][4];
        for (int nt = 0; nt < 4; ++nt) {
            f32x4 binit = *(const f32x4*)&sb[cur][nt * 16 + 4 * h];
            sacc[0][nt] = binit;
            sacc[1][nt] = binit;
        }
        for (int dk = 0; dk < 2; ++dk) {
            for (int nt = 0; nt < 4; ++nt) {
                bf16x8 kf = *(const bf16x8*)&Ks[cur][nt * 16 + q][dk * 32 + 8 * h];
                sacc[0][nt] = MFMA(kf, qf[0][dk], sacc[0][nt]);
                sacc[1][nt] = MFMA(kf, qf[1][dk], sacc[1][nt]);
            }
        }
        // p = exp2(s^T) packed straight into PV A-fragments (in registers)
        union pk_t { bf16x8 v; __hip_bfloat16 hh[8]; } pa[2][2];
        for (int m = 0; m < 2; ++m)
            for (int kk = 0; kk < 2; ++kk)
                for (int j = 0; j < 4; ++j) {
                    pa[m][kk].hh[j]     = __float2bfloat16(exp2f(sacc[m][kk][j]));
                    pa[m][kk].hh[j + 4] = __float2bfloat16(exp2f(sacc[m][kk + 2][j]));
                }
        // acc += P @ V ; lsum += P @ ones  (V columns permuted to match)
        for (int kk = 0; kk < 2; ++kk) {
            lsum[0] = MFMA(pa[0][kk].v, ones, lsum[0]);
            lsum[1] = MFMA(pa[1][kk].v, ones, lsum[1]);
            for (int dt = 0; dt < 4; ++dt) {
                bf16x8 bv = *(const bf16x8*)&VTs[cur][dt * 16 + q][kk * 32 + 8 * h];
                acc[0][dt] = MFMA(pa[0][kk].v, bv, acc[0][dt]);
                acc[1][dt] = MFMA(pa[1][kk].v, bv, acc[1][dt]);
            }
        }
        __syncthreads();   // writes to buf[cur^1] done; reads of buf[cur] done
    }

    // lane's lsum[m][jj] IS the row-sum for acc row jj of subtile m
    for (int m = 0; m < 2; ++m) {
        float rinv[4];
        for (int jj = 0; jj < 4; ++jj) rinv[jj] = 1.f / lsum[m][jj];
        const int ibase = qt * 128 + w * 32 + m * 16 + 4 * h;
        for (int dt = 0; dt < 4; ++dt) {
            int d = dt * 16 + q;
            union { __hip_bfloat16 hh[4]; uint2 u; } o;
            for (int jj = 0; jj < 4; ++jj)
                o.hh[jj] = __float2bfloat16(acc[m][dt][jj] * rinv[jj]);
            *(uint2*)(wvt + (size_t)g * (HD * SEQ) + (size_t)d * SEQ + ibase) = o.u;
        }
    }
}

// ---------------------------------------------------------------------------
// ws layout (26MB + 8.2KB): Xb [0,8MB) -> aliased by wvt after QKV GEMM;
// W bf16 [8,10MB) (Wq,Wk,Wv,Wo contiguous); qb [10,18MB); kc [18,26MB);
// hdr [26MB, +8.2KB) = {nvalid, cidx[2048]}. vT lives in d_out's first 8 MB.
// No pad-zero kernel: attn sanitizes tail loads in-register (ktail/vtail).
// ---------------------------------------------------------------------------
extern "C" void kernel_launch(void* const* d_in, const int* in_sizes, int n_in,
                              void* d_out, int out_size, void* d_ws, size_t ws_size,
                              hipStream_t stream) {
    const float* lstm = (const float*)d_in[0];
    const int* mask = (const int*)d_in[1];
    const float* Wq = (const float*)d_in[2]; const float* bq = (const float*)d_in[3];
    const float* Wk = (const float*)d_in[4]; const float* bk = (const float*)d_in[5];
    const float* Wv = (const float*)d_in[6]; const float* bv = (const float*)d_in[7];
    const float* Wo = (const float*)d_in[8]; const float* bo = (const float*)d_in[9];
    float* out = (float*)d_out;

    const size_t NX = (size_t)MROWS * HID;    // 4M elems
    const size_t NW = (size_t)HID * HID;      // 256K elems
    __hip_bfloat16* Xb  = (__hip_bfloat16*)d_ws;            // 4M elems (8MB)
    __hip_bfloat16* Wqb = Xb + NX;                          // 256K
    __hip_bfloat16* Wkb = Wqb + NW;
    __hip_bfloat16* Wvb = Wkb + NW;
    __hip_bfloat16* Wob = Wvb + NW;
    __hip_bfloat16* qb  = Wob + NW;                         // 4M
    __hip_bfloat16* kc  = qb + NX;                          // 4M (compacted K)
    int*            hdr = (int*)(kc + NX);                  // 1 + 2048 ints
    __hip_bfloat16* vT  = (__hip_bfloat16*)d_out;           // scratch in d_out[0,8MB)
    __hip_bfloat16* wvt = Xb;                               // alias: Xb dead after QKV GEMM

    prep<<<3073, 256, 0, stream>>>(lstm, Wq, Wk, Wv, Wo, mask, Xb, Wqb, hdr);

    dim3 gg(MROWS / 64, HID / 64), bb(256);
    gemm_qkv_fused<<<gg, bb, 0, stream>>>(Xb, Wqb, Wkb, Wvb, bq, bk, bv, hdr, qb, kc, vT);
    attn<<<dim3(NG * (SEQ / 128)), bb, 0, stream>>>(qb, kc, vT, hdr, wvt);
    gemm_out<<<gg, bb, 0, stream>>>(wvt, Wob, bo, out);
}